// Round 1
// baseline (2033.596 us; speedup 1.0000x reference)
//
#include <hip/hip_runtime.h>

typedef _Float16 fp16_t;
typedef __attribute__((ext_vector_type(8))) _Float16 f16x8;
typedef __attribute__((ext_vector_type(4))) _Float16 f16x4;
typedef __attribute__((ext_vector_type(4))) float f32x4;

#define N_TOK 8192
#define DIM   1024
#define HID   2048
#define OUTD  1024
#define NE    8
#define NPAIR 16384   // N_TOK * top_k

// -------------------------------------------------------------------------
// async global->LDS, 16B per lane (wave-uniform base + lane*16 layout)
// -------------------------------------------------------------------------
__device__ __forceinline__ void load_lds16(const void* g, void* l) {
    __builtin_amdgcn_global_load_lds(
        (__attribute__((address_space(1))) void*)g,
        (__attribute__((address_space(3))) void*)l, 16, 0, 0);
}

// -------------------------------------------------------------------------
// init: zero the per-expert counters
// -------------------------------------------------------------------------
__global__ void init_kernel(int* counts) {
    if (threadIdx.x < NE) counts[threadIdx.x] = 0;
}

// -------------------------------------------------------------------------
// gating: fp32, one wave handles 4 tokens (x rows staged in LDS).
// gates = softmax(relu(x@Wg1+bg1)@Wg2+bg2); top-2 (ties -> lower index,
// matching jax.lax.top_k); combine weights are the ORIGINAL gate values.
// -------------------------------------------------------------------------
__global__ __launch_bounds__(256) void gating_kernel(
    const float* __restrict__ x,  const float* __restrict__ Wg1,
    const float* __restrict__ bg1, const float* __restrict__ Wg2,
    const float* __restrict__ bg2, int* __restrict__ counts,
    int* __restrict__ top_i, float* __restrict__ top_w)
{
    __shared__ float xs[16][DIM];           // 64 KB: 16 token rows
    const int tid = threadIdx.x, lane = tid & 63, wv = tid >> 6;

    const float4* x4 = (const float4*)(x + (size_t)blockIdx.x * 16 * DIM);
    float4* xs4 = (float4*)&xs[0][0];
    #pragma unroll 4
    for (int i = tid; i < 16 * DIM / 4; i += 256) xs4[i] = x4[i];
    __syncthreads();

    const int trow = wv * 4;                // this wave's 4 tokens
    float b = bg1[lane];
    float hg[4] = {b, b, b, b};             // lane 'lane' owns hidden unit 'lane'
    for (int d0 = 0; d0 < DIM; d0 += 4) {
        float w0 = Wg1[(d0 + 0) * 64 + lane];
        float w1 = Wg1[(d0 + 1) * 64 + lane];
        float w2 = Wg1[(d0 + 2) * 64 + lane];
        float w3 = Wg1[(d0 + 3) * 64 + lane];
        #pragma unroll
        for (int t = 0; t < 4; ++t) {
            float4 a = *(const float4*)&xs[trow + t][d0];
            hg[t] = fmaf(a.x, w0, fmaf(a.y, w1, fmaf(a.z, w2, fmaf(a.w, w3, hg[t]))));
        }
    }

    #pragma unroll
    for (int t = 0; t < 4; ++t) {
        float h = fmaxf(hg[t], 0.f);
        float p[NE];
        #pragma unroll
        for (int e = 0; e < NE; ++e) p[e] = h * Wg2[lane * NE + e];
        #pragma unroll
        for (int s = 32; s > 0; s >>= 1) {
            #pragma unroll
            for (int e = 0; e < NE; ++e) p[e] += __shfl_xor(p[e], s, 64);
        }
        if (lane == 0) {
            int n = blockIdx.x * 16 + trow + t;
            float g[NE];
            float m = -1e30f;
            #pragma unroll
            for (int e = 0; e < NE; ++e) { g[e] = p[e] + bg2[e]; m = fmaxf(m, g[e]); }
            float s = 0.f;
            #pragma unroll
            for (int e = 0; e < NE; ++e) { g[e] = expf(g[e] - m); s += g[e]; }
            float inv = 1.f / s;
            #pragma unroll
            for (int e = 0; e < NE; ++e) g[e] *= inv;
            int b0 = 0;
            #pragma unroll
            for (int e = 1; e < NE; ++e) if (g[e] > g[b0]) b0 = e;
            int b1 = (b0 == 0) ? 1 : 0;
            #pragma unroll
            for (int e = 0; e < NE; ++e) if (e != b0 && g[e] > g[b1]) b1 = e;
            top_i[n] = b0;          top_i[N_TOK + n] = b1;
            top_w[n] = g[b0];       top_w[N_TOK + n] = g[b1];
            atomicAdd(&counts[b0], 1); atomicAdd(&counts[b1], 1);
        }
    }
}

// -------------------------------------------------------------------------
// exclusive scan over 8 expert counts (trivial)
// -------------------------------------------------------------------------
__global__ void scan_kernel(const int* __restrict__ counts,
                            int* __restrict__ offs, int* __restrict__ cursor) {
    if (threadIdx.x == 0) {
        int acc = 0;
        for (int e = 0; e < NE; ++e) { offs[e] = acc; cursor[e] = acc; acc += counts[e]; }
        offs[NE] = acc;
    }
}

// -------------------------------------------------------------------------
// scatter: token -> per-expert contiguous pair list; record slot per token
// -------------------------------------------------------------------------
__global__ __launch_bounds__(256) void scatter_kernel(
    const int* __restrict__ top_i, int* __restrict__ cursor,
    int* __restrict__ pair_token, int* __restrict__ slot)
{
    int n = blockIdx.x * 256 + threadIdx.x;
    if (n >= N_TOK) return;
    #pragma unroll
    for (int s = 0; s < 2; ++s) {
        int e = top_i[s * N_TOK + n];
        int p = atomicAdd(&cursor[e], 1);
        pair_token[p] = n;
        slot[s * N_TOK + n] = p;
    }
}

// -------------------------------------------------------------------------
// x -> fp16
// -------------------------------------------------------------------------
__global__ __launch_bounds__(256) void xcvt_kernel(
    const float* __restrict__ x, fp16_t* __restrict__ xb)
{
    size_t i = ((size_t)blockIdx.x * 256 + threadIdx.x) * 4;
    float4 v = *(const float4*)(x + i);
    f16x4 o = { (fp16_t)v.x, (fp16_t)v.y, (fp16_t)v.z, (fp16_t)v.w };
    *(f16x4*)(xb + i) = o;
}

// -------------------------------------------------------------------------
// batched transpose+convert: src fp32 [batch][R][C] -> dst fp16 [batch][C][R]
// (puts the GEMM contraction axis contiguous for MFMA k-fragments)
// -------------------------------------------------------------------------
__global__ __launch_bounds__(256) void transpose_cvt(
    const float* __restrict__ src, fp16_t* __restrict__ dst, int R, int C)
{
    int bb = blockIdx.z;
    src += (size_t)bb * R * C;
    dst += (size_t)bb * R * C;
    __shared__ float sm[32][33];
    int tx = threadIdx.x & 31, ty = threadIdx.x >> 5;   // 32 x 8
    int r0 = blockIdx.y * 32, c0 = blockIdx.x * 32;
    #pragma unroll
    for (int i = 0; i < 4; ++i)
        sm[ty + 8 * i][tx] = src[(size_t)(r0 + ty + 8 * i) * C + c0 + tx];
    __syncthreads();
    #pragma unroll
    for (int i = 0; i < 4; ++i)
        dst[(size_t)(c0 + ty + 8 * i) * R + r0 + tx] = (fp16_t)sm[tx][ty + 8 * i];
}

// -------------------------------------------------------------------------
// expert GEMM: C[m,n] = act(A[m,:] . Wt[e][n,:] + bias[e][n])
//   A: fp16 [*][K]  (GATHER: row = pair_token[pair], else row = pair)
//   Wt: fp16 [NE][NOUT][K]  (pre-transposed)
// 128x128 tile, BK=64, 4 waves 2x2, 16x16x32 f16 MFMA, DMA staging (m97).
// LDS layout: addr(row,kg) = kg*2048 + row*16 -> conflict-free ds_read_b128.
// -------------------------------------------------------------------------
template <int K, int NOUT, bool GATHER, bool RELU, bool OUT_FP16>
__global__ __launch_bounds__(256) void gemm_expert(
    const fp16_t* __restrict__ A, const fp16_t* __restrict__ Wt,
    const float* __restrict__ bias, void* __restrict__ Cout,
    const int* __restrict__ offs, const int* __restrict__ pair_token)
{
    const int e  = blockIdx.x >> 6;
    const int mt = blockIdx.x & 63;
    const int off = offs[e];
    const int cnt = offs[e + 1] - off;
    if (mt * 128 >= cnt) return;
    const int rows_here = min(128, cnt - mt * 128);
    const int mb = off + mt * 128;
    const int n0 = blockIdx.y * 128;

    const int tid = threadIdx.x, lane = tid & 63, wv = tid >> 6;
    const int wm = wv & 1, wn = wv >> 1;

    __shared__ __align__(16) char smem[32768];
    char* As = smem;            // 16 KB
    char* Bs = smem + 16384;    // 16 KB

    // per-lane A row base pointers (row-halves 0/1), clamped for tail tiles
    const fp16_t* arow[2];
    #pragma unroll
    for (int rh = 0; rh < 2; ++rh) {
        int i = rh * 64 + lane;
        int r = (i < rows_here) ? i : 0;
        long rowidx = GATHER ? (long)pair_token[mb + r] : (long)(mb + r);
        arow[rh] = A + rowidx * (long)K;
    }
    const fp16_t* We = Wt + (size_t)e * NOUT * K;
    const fp16_t* brow[2];
    #pragma unroll
    for (int nh = 0; nh < 2; ++nh)
        brow[nh] = We + (size_t)(n0 + nh * 64 + lane) * K;

    f32x4 acc[4][4] = {};

    for (int k0 = 0; k0 < K; k0 += 64) {
        __syncthreads();    // LDS safe to overwrite
        #pragma unroll
        for (int t = 0; t < 4; ++t) {       // A: 16 chunks over 4 waves
            int g = t * 4 + wv;
            int rh = g & 1, kg = g >> 1;
            load_lds16(arow[rh] + k0 + kg * 8,
                       As + kg * 2048 + rh * 1024 + lane * 16);
        }
        #pragma unroll
        for (int t = 0; t < 4; ++t) {       // B: 16 chunks over 4 waves
            int g = t * 4 + wv;
            int nh = g & 1, kg = g >> 1;
            load_lds16(brow[nh] + k0 + kg * 8,
                       Bs + kg * 2048 + nh * 1024 + lane * 16);
        }
        __syncthreads();    // staging complete

        const int quad = lane >> 4, l15 = lane & 15;
        #pragma unroll
        for (int ks = 0; ks < 2; ++ks) {
            int kg = ks * 4 + quad;
            f16x8 af[4], bf[4];
            #pragma unroll
            for (int i = 0; i < 4; ++i) {
                int m = wm * 64 + i * 16 + l15;
                af[i] = *(const f16x8*)(As + kg * 2048 + m * 16);
            }
            #pragma unroll
            for (int j = 0; j < 4; ++j) {
                int n = wn * 64 + j * 16 + l15;
                bf[j] = *(const f16x8*)(Bs + kg * 2048 + n * 16);
            }
            #pragma unroll
            for (int i = 0; i < 4; ++i)
                #pragma unroll
                for (int j = 0; j < 4; ++j)
                    acc[i][j] = __builtin_amdgcn_mfma_f32_16x16x32_f16(
                        af[i], bf[j], acc[i][j], 0, 0, 0);
        }
    }

    // epilogue: C/D layout col=lane&15, row=quad*4+reg
    const float* be = bias + (size_t)e * NOUT + n0;
    #pragma unroll
    for (int j = 0; j < 4; ++j) {
        int col = wn * 64 + j * 16 + (lane & 15);
        float bv = be[col];
        #pragma unroll
        for (int i = 0; i < 4; ++i) {
            int mrow0 = wm * 64 + i * 16 + ((lane >> 4) << 2);
            #pragma unroll
            for (int r = 0; r < 4; ++r) {
                int m = mrow0 + r;
                if (m < rows_here) {
                    float v = acc[i][j][r] + bv;
                    if (RELU) v = fmaxf(v, 0.f);
                    size_t o = (size_t)(mb + m) * NOUT + n0 + col;
                    if (OUT_FP16) ((fp16_t*)Cout)[o] = (fp16_t)v;
                    else          ((float*)Cout)[o]  = v;
                }
            }
        }
    }
}

// -------------------------------------------------------------------------
// combine: out[n,:] = w0*y[slot0[n],:] + w1*y[slot1[n],:]
// -------------------------------------------------------------------------
__global__ __launch_bounds__(256) void combine_kernel(
    const float* __restrict__ y, const int* __restrict__ slot,
    const float* __restrict__ top_w, float* __restrict__ out)
{
    int idx = blockIdx.x * 256 + threadIdx.x;    // over N_TOK * OUTD/4
    int n  = idx >> 8;                           // OUTD/4 = 256
    int o4 = idx & 255;
    int s0 = slot[n], s1 = slot[N_TOK + n];
    float w0 = top_w[n], w1 = top_w[N_TOK + n];
    float4 y0 = *(const float4*)(y + (size_t)s0 * OUTD + o4 * 4);
    float4 y1 = *(const float4*)(y + (size_t)s1 * OUTD + o4 * 4);
    float4 r;
    r.x = w0 * y0.x + w1 * y1.x;
    r.y = w0 * y0.y + w1 * y1.y;
    r.z = w0 * y0.z + w1 * y1.z;
    r.w = w0 * y0.w + w1 * y1.w;
    *(float4*)(out + (size_t)n * OUTD + o4 * 4) = r;
}

// -------------------------------------------------------------------------
extern "C" void kernel_launch(void* const* d_in, const int* in_sizes, int n_in,
                              void* d_out, int out_size, void* d_ws, size_t ws_size,
                              hipStream_t stream)
{
    (void)in_sizes; (void)n_in; (void)out_size; (void)ws_size;
    const float* x   = (const float*)d_in[0];
    const float* W1  = (const float*)d_in[1];
    const float* b1  = (const float*)d_in[2];
    const float* W2  = (const float*)d_in[3];
    const float* b2  = (const float*)d_in[4];
    const float* W3  = (const float*)d_in[5];
    const float* b3  = (const float*)d_in[6];
    const float* Wg1 = (const float*)d_in[7];
    const float* bg1 = (const float*)d_in[8];
    const float* Wg2 = (const float*)d_in[9];
    const float* bg2 = (const float*)d_in[10];

    // ws layout (bytes):
    //   xb   @ 0          : 16,777,216   (8192x1024 fp16)
    //   h1/y @ 16777216   : 67,108,864   (16384x2048 fp16 == 16384x1024 fp32)
    //   h2   @ 83886080   : 67,108,864
    //   Wt   @ 150994944  : 67,108,864   (max of transposed W1/W2/W3, fp16)
    //   rt   @ 218103808  : routing (~0.3 MB)   -> total ~218.4 MB
    char* ws = (char*)d_ws;
    fp16_t* xb = (fp16_t*)ws;
    fp16_t* h1 = (fp16_t*)(ws + 16777216);
    fp16_t* h2 = (fp16_t*)(ws + 83886080);
    fp16_t* Wt = (fp16_t*)(ws + 150994944);
    char* rt   = ws + 218103808;
    int*   counts     = (int*)rt;
    int*   offs       = counts + 8;
    int*   cursor     = offs + 9;
    int*   top_i      = cursor + 8;                  // 2*N
    float* top_w      = (float*)(top_i + 2 * N_TOK); // 2*N
    int*   slot       = (int*)(top_w + 2 * N_TOK);   // 2*N
    int*   pair_token = slot + 2 * N_TOK;            // NPAIR

    init_kernel<<<1, 64, 0, stream>>>(counts);
    gating_kernel<<<512, 256, 0, stream>>>(x, Wg1, bg1, Wg2, bg2, counts, top_i, top_w);
    scan_kernel<<<1, 64, 0, stream>>>(counts, offs, cursor);
    scatter_kernel<<<32, 256, 0, stream>>>(top_i, cursor, pair_token, slot);
    xcvt_kernel<<<8192, 256, 0, stream>>>(x, xb);

    // L1: h1 = relu(x @ W1[e] + b1[e])   (gathered rows, K=1024, NOUT=2048)
    transpose_cvt<<<dim3(HID / 32, DIM / 32, NE), 256, 0, stream>>>(W1, Wt, DIM, HID);
    gemm_expert<DIM, HID, true, true, true>
        <<<dim3(512, HID / 128), 256, 0, stream>>>(xb, Wt, b1, (void*)h1, offs, pair_token);

    // L2: h2 = relu(h1 @ W2[e] + b2[e])  (K=2048, NOUT=2048)
    transpose_cvt<<<dim3(HID / 32, HID / 32, NE), 256, 0, stream>>>(W2, Wt, HID, HID);
    gemm_expert<HID, HID, false, true, true>
        <<<dim3(512, HID / 128), 256, 0, stream>>>(h1, Wt, b2, (void*)h2, offs, pair_token);

    // L3: y = h2 @ W3[e] + b3[e]  (fp32 out into h1's buffer; K=2048, NOUT=1024)
    transpose_cvt<<<dim3(OUTD / 32, HID / 32, NE), 256, 0, stream>>>(W3, Wt, HID, OUTD);
    gemm_expert<HID, OUTD, false, false, false>
        <<<dim3(512, OUTD / 128), 256, 0, stream>>>(h2, Wt, b3, (void*)h1, offs, pair_token);

    combine_kernel<<<8192, 256, 0, stream>>>((const float*)h1, slot, top_w, (float*)d_out);
}

// Round 2
// 1182.543 us; speedup vs baseline: 1.7197x; 1.7197x over previous
//
#include <hip/hip_runtime.h>

typedef _Float16 fp16_t;
typedef __attribute__((ext_vector_type(8))) _Float16 f16x8;
typedef __attribute__((ext_vector_type(4))) _Float16 f16x4;
typedef __attribute__((ext_vector_type(4))) float f32x4;

#define N_TOK 8192
#define DIM   1024
#define HID   2048
#define OUTD  1024
#define NE    8
#define NPAIR 16384    // N_TOK * top_k
#define MAXSLOT 136    // max m-tiles: 16384/128 + 8 partial

// -------------------------------------------------------------------------
// async global->LDS, 16B per lane (wave-uniform LDS base + lane*16; global
// address may be per-lane)
// -------------------------------------------------------------------------
__device__ __forceinline__ void load_lds16(const void* g, void* l) {
    __builtin_amdgcn_global_load_lds(
        (__attribute__((address_space(1))) void*)g,
        (__attribute__((address_space(3))) void*)l, 16, 0, 0);
}

// -------------------------------------------------------------------------
__global__ void init_kernel(int* counts) {
    if (threadIdx.x < NE) counts[threadIdx.x] = 0;
}

// -------------------------------------------------------------------------
// gating: fp32, one wave handles 4 tokens (x rows staged in LDS).
// top-2 ties -> lower index (matches jax.lax.top_k); combine weight = the
// ORIGINAL gate value.
// -------------------------------------------------------------------------
__global__ __launch_bounds__(256) void gating_kernel(
    const float* __restrict__ x,  const float* __restrict__ Wg1,
    const float* __restrict__ bg1, const float* __restrict__ Wg2,
    const float* __restrict__ bg2, int* __restrict__ counts,
    int* __restrict__ top_i, float* __restrict__ top_w)
{
    __shared__ float xs[16][DIM];           // 64 KB: 16 token rows
    const int tid = threadIdx.x, lane = tid & 63, wv = tid >> 6;

    const float4* x4 = (const float4*)(x + (size_t)blockIdx.x * 16 * DIM);
    float4* xs4 = (float4*)&xs[0][0];
    #pragma unroll 4
    for (int i = tid; i < 16 * DIM / 4; i += 256) xs4[i] = x4[i];
    __syncthreads();

    const int trow = wv * 4;
    float b = bg1[lane];
    float hg[4] = {b, b, b, b};             // lane owns hidden unit 'lane'
    for (int d0 = 0; d0 < DIM; d0 += 4) {
        float w0 = Wg1[(d0 + 0) * 64 + lane];
        float w1 = Wg1[(d0 + 1) * 64 + lane];
        float w2 = Wg1[(d0 + 2) * 64 + lane];
        float w3 = Wg1[(d0 + 3) * 64 + lane];
        #pragma unroll
        for (int t = 0; t < 4; ++t) {
            float4 a = *(const float4*)&xs[trow + t][d0];
            hg[t] = fmaf(a.x, w0, fmaf(a.y, w1, fmaf(a.z, w2, fmaf(a.w, w3, hg[t]))));
        }
    }

    #pragma unroll
    for (int t = 0; t < 4; ++t) {
        float h = fmaxf(hg[t], 0.f);
        float p[NE];
        #pragma unroll
        for (int e = 0; e < NE; ++e) p[e] = h * Wg2[lane * NE + e];
        #pragma unroll
        for (int s = 32; s > 0; s >>= 1) {
            #pragma unroll
            for (int e = 0; e < NE; ++e) p[e] += __shfl_xor(p[e], s, 64);
        }
        if (lane == 0) {
            int n = blockIdx.x * 16 + trow + t;
            float g[NE];
            float m = -1e30f;
            #pragma unroll
            for (int e = 0; e < NE; ++e) { g[e] = p[e] + bg2[e]; m = fmaxf(m, g[e]); }
            float s = 0.f;
            #pragma unroll
            for (int e = 0; e < NE; ++e) { g[e] = expf(g[e] - m); s += g[e]; }
            float inv = 1.f / s;
            #pragma unroll
            for (int e = 0; e < NE; ++e) g[e] *= inv;
            int b0 = 0;
            #pragma unroll
            for (int e = 1; e < NE; ++e) if (g[e] > g[b0]) b0 = e;
            int b1 = (b0 == 0) ? 1 : 0;
            #pragma unroll
            for (int e = 0; e < NE; ++e) if (e != b0 && g[e] > g[b1]) b1 = e;
            top_i[n] = b0;          top_i[N_TOK + n] = b1;
            top_w[n] = g[b0];       top_w[N_TOK + n] = g[b1];
            atomicAdd(&counts[b0], 1); atomicAdd(&counts[b1], 1);
        }
    }
}

// -------------------------------------------------------------------------
// scan + build m-tile table (slot -> expert, m-tile)
// -------------------------------------------------------------------------
__global__ void scan_kernel(const int* __restrict__ counts,
                            int* __restrict__ offs, int* __restrict__ cursor,
                            int* __restrict__ tile_e, int* __restrict__ tile_mt) {
    if (threadIdx.x == 0) {
        int acc = 0;
        for (int e = 0; e < NE; ++e) { offs[e] = acc; cursor[e] = acc; acc += counts[e]; }
        offs[NE] = acc;
        int s = 0;
        for (int e = 0; e < NE; ++e) {
            int nt = (counts[e] + 127) >> 7;
            for (int mt = 0; mt < nt; ++mt) { tile_e[s] = e; tile_mt[s] = mt; ++s; }
        }
        for (; s < MAXSLOT; ++s) tile_e[s] = -1;
    }
}

// -------------------------------------------------------------------------
__global__ __launch_bounds__(256) void scatter_kernel(
    const int* __restrict__ top_i, int* __restrict__ cursor,
    int* __restrict__ pair_token, int* __restrict__ slot)
{
    int n = blockIdx.x * 256 + threadIdx.x;
    if (n >= N_TOK) return;
    #pragma unroll
    for (int s = 0; s < 2; ++s) {
        int e = top_i[s * N_TOK + n];
        int p = atomicAdd(&cursor[e], 1);
        pair_token[p] = n;
        slot[s * N_TOK + n] = p;
    }
}

// -------------------------------------------------------------------------
__global__ __launch_bounds__(256) void xcvt_kernel(
    const float* __restrict__ x, fp16_t* __restrict__ xb)
{
    size_t i = ((size_t)blockIdx.x * 256 + threadIdx.x) * 4;
    float4 v = *(const float4*)(x + i);
    f16x4 o = { (fp16_t)v.x, (fp16_t)v.y, (fp16_t)v.z, (fp16_t)v.w };
    *(f16x4*)(xb + i) = o;
}

// -------------------------------------------------------------------------
// batched transpose+convert: src fp32 [batch][R][C] -> dst fp16 [batch][C][R]
// -------------------------------------------------------------------------
__global__ __launch_bounds__(256) void transpose_cvt(
    const float* __restrict__ src, fp16_t* __restrict__ dst, int R, int C)
{
    int bb = blockIdx.z;
    src += (size_t)bb * R * C;
    dst += (size_t)bb * R * C;
    __shared__ float sm[32][33];
    int tx = threadIdx.x & 31, ty = threadIdx.x >> 5;   // 32 x 8
    int r0 = blockIdx.y * 32, c0 = blockIdx.x * 32;
    #pragma unroll
    for (int i = 0; i < 4; ++i)
        sm[ty + 8 * i][tx] = src[(size_t)(r0 + ty + 8 * i) * C + c0 + tx];
    __syncthreads();
    #pragma unroll
    for (int i = 0; i < 4; ++i)
        dst[(size_t)(c0 + ty + 8 * i) * R + r0 + tx] = (fp16_t)sm[tx][ty + 8 * i];
}

// -------------------------------------------------------------------------
// expert GEMM: C[m,n] = act(A[m,:] . Wt[e][n,:] + bias[e][n])
// 128x128 tile, BK=64, 4 waves 2x2, 16x16x32 f16 MFMA.
//
// Staging (coalesced + XOR-swizzled):
//   instruction rg (0..15) covers rows rg*8..rg*8+7 of the tile.
//   lane l: row = rg*8 + (l>>3); global chunk = (l&7) ^ (l>>3)  (16B units).
//   -> each 8-lane group covers one full aligned 128B line (permuted within
//      the line: coalescing unaffected). 8 lines/instruction, all consumed.
//   LDS: As[row][slot]*16B with slot = chunk ^ (row&7); reader computes
//   slot = kg ^ (m&7) -> per-16-lane phase every bank hit exactly 2x (free).
//   Since row mod 8 == l>>3 for every instruction, the chunk offset is a
//   lane constant folded into the row base pointer.
// -------------------------------------------------------------------------
template <int K, int NOUT, bool GATHER, bool RELU, bool OUT_FP16>
__global__ __launch_bounds__(256) void gemm_expert(
    const fp16_t* __restrict__ A, const fp16_t* __restrict__ Wt,
    const float* __restrict__ bias, void* __restrict__ Cout,
    const int* __restrict__ offs, const int* __restrict__ pair_token,
    const int* __restrict__ tile_e, const int* __restrict__ tile_mt)
{
    const int e = tile_e[blockIdx.y];
    if (e < 0) return;
    const int mt  = tile_mt[blockIdx.y];
    const int off = offs[e];
    const int cnt = offs[e + 1] - off;
    const int rows_here = min(128, cnt - mt * 128);
    const int mb = off + mt * 128;
    const int n0 = blockIdx.x * 128;

    const int tid = threadIdx.x, lane = tid & 63, wv = tid >> 6;
    const int wm = wv & 1, wn = wv >> 1;

    __shared__ __align__(16) char smem[32768];
    char* As = smem;            // 16 KB: [row128][slot8]*16B
    char* Bs = smem + 16384;    // 16 KB

    const int lr   = lane >> 3;                 // row-in-group 0..7
    const int coff = (((lane & 7) ^ lr)) * 8;   // element offset of lane's chunk

    const fp16_t* We = Wt + (size_t)e * NOUT * K;
    const fp16_t* ag[4];
    const fp16_t* bg[4];
    #pragma unroll
    for (int t = 0; t < 4; ++t) {
        int r = wv * 32 + t * 8 + lr;           // tile row 0..127
        int rc = (r < rows_here) ? r : 0;       // clamp for tail tiles
        long rowidx = GATHER ? (long)pair_token[mb + rc] : (long)(mb + rc);
        ag[t] = A + rowidx * (long)K + coff;
        bg[t] = We + (size_t)(n0 + r) * K + coff;
    }

    f32x4 acc[4][4] = {};

    for (int k0 = 0; k0 < K; k0 += 64) {
        __syncthreads();    // LDS safe to overwrite
        #pragma unroll
        for (int t = 0; t < 4; ++t) {
            int rg = wv * 4 + t;
            load_lds16(ag[t] + k0, As + rg * 1024);
            load_lds16(bg[t] + k0, Bs + rg * 1024);
        }
        __syncthreads();    // staging complete

        const int quad = lane >> 4, l15 = lane & 15, sb = l15 & 7;
        #pragma unroll
        for (int ks = 0; ks < 2; ++ks) {
            int kg = ks * 4 + quad;
            int sl = (kg ^ sb) * 16;
            f16x8 af[4], bf[4];
            #pragma unroll
            for (int i = 0; i < 4; ++i) {
                int m = wm * 64 + i * 16 + l15;
                af[i] = *(const f16x8*)(As + m * 128 + sl);
            }
            #pragma unroll
            for (int j = 0; j < 4; ++j) {
                int n = wn * 64 + j * 16 + l15;
                bf[j] = *(const f16x8*)(Bs + n * 128 + sl);
            }
            #pragma unroll
            for (int i = 0; i < 4; ++i)
                #pragma unroll
                for (int j = 0; j < 4; ++j)
                    acc[i][j] = __builtin_amdgcn_mfma_f32_16x16x32_f16(
                        af[i], bf[j], acc[i][j], 0, 0, 0);
        }
    }

    // epilogue: C/D layout col=lane&15, row=quad*4+reg
    const float* be = bias + (size_t)e * NOUT + n0;
    #pragma unroll
    for (int j = 0; j < 4; ++j) {
        int col = wn * 64 + j * 16 + (lane & 15);
        float bv = be[col];
        #pragma unroll
        for (int i = 0; i < 4; ++i) {
            int mrow0 = wm * 64 + i * 16 + ((lane >> 4) << 2);
            #pragma unroll
            for (int r = 0; r < 4; ++r) {
                int m = mrow0 + r;
                if (m < rows_here) {
                    float v = acc[i][j][r] + bv;
                    if (RELU) v = fmaxf(v, 0.f);
                    size_t o = (size_t)(mb + m) * NOUT + n0 + col;
                    if (OUT_FP16) ((fp16_t*)Cout)[o] = (fp16_t)v;
                    else          ((float*)Cout)[o]  = v;
                }
            }
        }
    }
}

// -------------------------------------------------------------------------
__global__ __launch_bounds__(256) void combine_kernel(
    const float* __restrict__ y, const int* __restrict__ slot,
    const float* __restrict__ top_w, float* __restrict__ out)
{
    int idx = blockIdx.x * 256 + threadIdx.x;    // over N_TOK * OUTD/4
    int n  = idx >> 8;                           // OUTD/4 = 256
    int o4 = idx & 255;
    int s0 = slot[n], s1 = slot[N_TOK + n];
    float w0 = top_w[n], w1 = top_w[N_TOK + n];
    float4 y0 = *(const float4*)(y + (size_t)s0 * OUTD + o4 * 4);
    float4 y1 = *(const float4*)(y + (size_t)s1 * OUTD + o4 * 4);
    float4 r;
    r.x = w0 * y0.x + w1 * y1.x;
    r.y = w0 * y0.y + w1 * y1.y;
    r.z = w0 * y0.z + w1 * y1.z;
    r.w = w0 * y0.w + w1 * y1.w;
    *(float4*)(out + (size_t)n * OUTD + o4 * 4) = r;
}

// -------------------------------------------------------------------------
extern "C" void kernel_launch(void* const* d_in, const int* in_sizes, int n_in,
                              void* d_out, int out_size, void* d_ws, size_t ws_size,
                              hipStream_t stream)
{
    (void)in_sizes; (void)n_in; (void)out_size; (void)ws_size;
    const float* x   = (const float*)d_in[0];
    const float* W1  = (const float*)d_in[1];
    const float* b1  = (const float*)d_in[2];
    const float* W2  = (const float*)d_in[3];
    const float* b2  = (const float*)d_in[4];
    const float* W3  = (const float*)d_in[5];
    const float* b3  = (const float*)d_in[6];
    const float* Wg1 = (const float*)d_in[7];
    const float* bg1 = (const float*)d_in[8];
    const float* Wg2 = (const float*)d_in[9];
    const float* bg2 = (const float*)d_in[10];

    // ws layout (bytes):
    //   xb   @ 0          : 16,777,216   (8192x1024 fp16)
    //   h1/y @ 16777216   : 67,108,864   (16384x2048 fp16 == 16384x1024 fp32)
    //   h2   @ 83886080   : 67,108,864
    //   Wt   @ 150994944  : 67,108,864   (max transposed W, fp16)
    //   rt   @ 218103808  : routing (~0.3 MB)
    char* ws = (char*)d_ws;
    fp16_t* xb = (fp16_t*)ws;
    fp16_t* h1 = (fp16_t*)(ws + 16777216);
    fp16_t* h2 = (fp16_t*)(ws + 83886080);
    fp16_t* Wt = (fp16_t*)(ws + 150994944);
    char* rt   = ws + 218103808;
    int*   counts     = (int*)rt;
    int*   offs       = counts + 8;
    int*   cursor     = offs + 9;
    int*   tile_e     = cursor + 8;                  // MAXSLOT
    int*   tile_mt    = tile_e + MAXSLOT;            // MAXSLOT
    int*   top_i      = tile_mt + MAXSLOT;           // 2*N
    float* top_w      = (float*)(top_i + 2 * N_TOK); // 2*N
    int*   slot       = (int*)(top_w + 2 * N_TOK);   // 2*N
    int*   pair_token = slot + 2 * N_TOK;            // NPAIR

    init_kernel<<<1, 64, 0, stream>>>(counts);
    gating_kernel<<<512, 256, 0, stream>>>(x, Wg1, bg1, Wg2, bg2, counts, top_i, top_w);
    scan_kernel<<<1, 64, 0, stream>>>(counts, offs, cursor, tile_e, tile_mt);
    scatter_kernel<<<32, 256, 0, stream>>>(top_i, cursor, pair_token, slot);
    xcvt_kernel<<<8192, 256, 0, stream>>>(x, xb);

    // grid.x = n-tiles so linear%8 == n-tile%8 -> per-XCD n-column affinity
    // L1: h1 = relu(x @ W1[e] + b1[e])   (gathered rows, K=1024, NOUT=2048)
    transpose_cvt<<<dim3(HID / 32, DIM / 32, NE), 256, 0, stream>>>(W1, Wt, DIM, HID);
    gemm_expert<DIM, HID, true, true, true>
        <<<dim3(HID / 128, MAXSLOT), 256, 0, stream>>>(
            xb, Wt, b1, (void*)h1, offs, pair_token, tile_e, tile_mt);

    // L2: h2 = relu(h1 @ W2[e] + b2[e])  (K=2048, NOUT=2048)
    transpose_cvt<<<dim3(HID / 32, HID / 32, NE), 256, 0, stream>>>(W2, Wt, HID, HID);
    gemm_expert<HID, HID, false, true, true>
        <<<dim3(HID / 128, MAXSLOT), 256, 0, stream>>>(
            h1, Wt, b2, (void*)h2, offs, pair_token, tile_e, tile_mt);

    // L3: y = h2 @ W3[e] + b3[e]  (fp32 out into h1's buffer; K=2048, NOUT=1024)
    transpose_cvt<<<dim3(OUTD / 32, HID / 32, NE), 256, 0, stream>>>(W3, Wt, HID, OUTD);
    gemm_expert<HID, OUTD, false, false, false>
        <<<dim3(OUTD / 128, MAXSLOT), 256, 0, stream>>>(
            h2, Wt, b3, (void*)h1, offs, pair_token, tile_e, tile_mt);

    combine_kernel<<<8192, 256, 0, stream>>>((const float*)h1, slot, top_w, (float*)d_out);
}